// Round 11
// baseline (437.111 us; speedup 1.0000x reference)
//
#include <hip/hip_runtime.h>
#include <hip/hip_bf16.h>
#include <math.h>

#define NNODE 20000
#define FIN   128
#define HC    256     // HEADS*HID
#define HEADS 8
#define HID   32
#define NEDGE 320000
#define ETOT  (NEDGE + NNODE)
#define NGRAPH 64
#define NCLS  10
#define MAXDEG 64     // P(deg>=64) ~ 1e-17 per node for Binomial(320k,1/20k)+1

typedef __attribute__((ext_vector_type(8))) short short8v;
typedef __attribute__((ext_vector_type(8))) unsigned short ushort8v;
typedef __attribute__((ext_vector_type(4))) float float4v;

__device__ __forceinline__ ushort f2bf(float f) {
    __hip_bfloat16 b = __float2bfloat16(f);
    return *(ushort*)&b;
}
__device__ __forceinline__ float bf2f(ushort u) {
    return __uint_as_float(((unsigned)u) << 16);
}

// ---------------- init: zero deg/psum + transpose/convert W1, W2 -------------

#define ZB_DEG ((NNODE + 255) / 256)                        // 79
#define ZB_PS  ((NGRAPH * HC + NGRAPH + 255) / 256)         // 65

__global__ __launch_bounds__(256) void init_kernel(const float* __restrict__ W1,
                                                   const float* __restrict__ W2,
                                                   ushort* __restrict__ W1t,
                                                   ushort* __restrict__ W2t,
                                                   int* __restrict__ deg,
                                                   float* __restrict__ psum) {
    int b = blockIdx.x;
    if (b < 128) {
        int e = b * 256 + threadIdx.x;
        int k = e >> 8, n = e & 255;
        W1t[(long)n * FIN + k] = f2bf(W1[(long)k * 256 + n]);
    } else if (b < 384) {
        int e = (b - 128) * 256 + threadIdx.x;
        int k = e >> 8, n = e & 255;
        W2t[(long)n * HC + k] = f2bf(W2[(long)k * 256 + n]);
    } else if (b < 384 + ZB_DEG) {
        int i = (b - 384) * 256 + threadIdx.x;
        if (i < NNODE) deg[i] = 0;
    } else {
        int i = (b - 384 - ZB_DEG) * 256 + threadIdx.x;
        if (i < NGRAPH * HC + NGRAPH) psum[i] = 0.f;
    }
}

// ---------------- slot-table CSR: one kernel, no scan ------------------------

__global__ __launch_bounds__(256) void fill_slots(const int* __restrict__ ei,
                                                  int* __restrict__ deg,
                                                  int* __restrict__ esrc) {
    int e = blockIdx.x * blockDim.x + threadIdx.x;
    if (e >= ETOT) return;
    int src, dst;
    if (e < NEDGE) { src = ei[e]; dst = ei[NEDGE + e]; }
    else           { src = e - NEDGE; dst = src; }
    int slot = atomicAdd(&deg[dst], 1);
    if (slot < MAXDEG) esrc[dst * MAXDEG + slot] = src;
}

// ---------------- bf16 MFMA GEMM + fused aL/aR epilogue ----------------------
// C[M,256] = A[M,K] @ Bt[256,K]^T. 64x64 tile, 4 waves x 32x32 quadrant, BK=64.

template<bool A_FP32>
__global__ __launch_bounds__(256) void gemm_mfma(const void* __restrict__ Aptr,
                                                 const ushort* __restrict__ Bt,
                                                 ushort* __restrict__ C,
                                                 const float* __restrict__ attL,
                                                 const float* __restrict__ attR,
                                                 float* __restrict__ aL,
                                                 float* __restrict__ aR,
                                                 int M, int K) {
    __shared__ __align__(16) ushort As[64][72];   // pitch 72: 2-way conflicts max (free)
    __shared__ __align__(16) ushort Bs[64][72];
    int tid = threadIdx.x;
    int rowBase = blockIdx.x * 64;
    int colBase = blockIdx.y * 64;
    int wave = tid >> 6;
    int l = tid & 63;
    int lm = l & 15;
    int quad = l >> 4;
    int r0 = (wave >> 1) * 32;
    int c0 = (wave & 1) * 32;

    float4v acc00 = {0.f, 0.f, 0.f, 0.f};
    float4v acc01 = acc00, acc10 = acc00, acc11 = acc00;

    for (int k0 = 0; k0 < K; k0 += 64) {
        if (A_FP32) {
            const float* A = (const float*)Aptr;
            #pragma unroll
            for (int q = 0; q < 4; q++) {
                int idx = tid + q * 256;          // 0..1023 float4 chunks
                int r   = idx >> 4;
                int kc  = (idx & 15) * 4;
                int grow = rowBase + r;
                float4 v = make_float4(0.f, 0.f, 0.f, 0.f);
                if (grow < M) v = *(const float4*)(A + (long)grow * K + k0 + kc);
                ushort4 o = { f2bf(v.x), f2bf(v.y), f2bf(v.z), f2bf(v.w) };
                *(ushort4*)&As[r][kc] = o;
            }
            #pragma unroll
            for (int q = 0; q < 2; q++) {
                int ch = tid + q * 256;
                int r  = ch >> 3;
                int kc = (ch & 7) * 8;
                *(short8v*)&Bs[r][kc] =
                    *(const short8v*)(Bt + (long)(colBase + r) * K + k0 + kc);
            }
        } else {
            const ushort* A = (const ushort*)Aptr;
            #pragma unroll
            for (int q = 0; q < 2; q++) {
                int ch = tid + q * 256;
                int r  = ch >> 3;
                int kc = (ch & 7) * 8;
                int grow = rowBase + r;
                short8v av = {};
                if (grow < M) av = *(const short8v*)(A + (long)grow * K + k0 + kc);
                *(short8v*)&As[r][kc] = av;
                *(short8v*)&Bs[r][kc] =
                    *(const short8v*)(Bt + (long)(colBase + r) * K + k0 + kc);
            }
        }
        __syncthreads();
        #pragma unroll
        for (int ks = 0; ks < 64; ks += 32) {
            int kb = ks + quad * 8;
            short8v a0 = *(const short8v*)&As[r0 + lm][kb];
            short8v a1 = *(const short8v*)&As[r0 + 16 + lm][kb];
            short8v b0 = *(const short8v*)&Bs[c0 + lm][kb];
            short8v b1 = *(const short8v*)&Bs[c0 + 16 + lm][kb];
            acc00 = __builtin_amdgcn_mfma_f32_16x16x32_bf16(a0, b0, acc00, 0, 0, 0);
            acc01 = __builtin_amdgcn_mfma_f32_16x16x32_bf16(a0, b1, acc01, 0, 0, 0);
            acc10 = __builtin_amdgcn_mfma_f32_16x16x32_bf16(a1, b0, acc10, 0, 0, 0);
            acc11 = __builtin_amdgcn_mfma_f32_16x16x32_bf16(a1, b1, acc11, 0, 0, 0);
        }
        __syncthreads();
    }

    // D mapping: col = lane&15, row = quad*4 + reg
    int cb = colBase + c0;            // multiple of 32 -> one head per wave
    int hd = cb >> 5;
    float al0 = attL[cb + lm], al1 = attL[cb + 16 + lm];
    float ar0 = attR[cb + lm], ar1 = attR[cb + 16 + lm];
    #pragma unroll
    for (int mi = 0; mi < 2; mi++) {
        float4v s0 = mi ? acc10 : acc00;
        float4v s1 = mi ? acc11 : acc01;
        #pragma unroll
        for (int r = 0; r < 4; r++) {
            int row = rowBase + r0 + mi * 16 + quad * 4 + r;
            float pl = s0[r] * al0 + s1[r] * al1;
            float pr = s0[r] * ar0 + s1[r] * ar1;
            #pragma unroll
            for (int s2 = 1; s2 < 16; s2 <<= 1) {
                pl += __shfl_xor(pl, s2);     // within 16-lane quad
                pr += __shfl_xor(pr, s2);
            }
            if (row < M) {
                C[(long)row * 256 + cb + lm]      = f2bf(s0[r]);
                C[(long)row * 256 + cb + 16 + lm] = f2bf(s1[r]);
                if (lm == 0) {
                    aL[row * 8 + hd] = pl;
                    aR[row * 8 + hd] = pr;
                }
            }
        }
    }
}

// ---------------- fused attention: 1 node/wave, 2 slots, 2-stage pipeline ----
// MODE 1: apply ELU, write bf16 out row (layer 1).
// MODE 2: no ELU; atomically pool result into psum[batch[node]] (layer 2) —
//         eliminates the 10 MB hbB round-trip and the pool dispatch entirely.

template<int MODE>
__global__ __launch_bounds__(256) void fused_attn(const ushort* __restrict__ h,
                                                  const int* __restrict__ degv,
                                                  const int* __restrict__ esrc,
                                                  const float* __restrict__ aL,
                                                  const float* __restrict__ aR,
                                                  const float* __restrict__ bias,
                                                  ushort* __restrict__ out,
                                                  const int* __restrict__ batch,
                                                  float* __restrict__ psum,
                                                  float* __restrict__ pcnt) {
    int wave = threadIdx.x >> 6;
    int node = blockIdx.x * 4 + wave;
    if (node >= NNODE) return;
    int l = threadIdx.x & 63;
    int slot = l >> 5;
    int lh = l & 31;
    int head = lh >> 2;

    const ushort8v* h8 = (const ushort8v*)h;
    ushort8v hiu = h8[(long)node * 32 + lh];
    float hi[8];
    #pragma unroll
    for (int c = 0; c < 8; c++) hi[c] = bf2f(hiu[c]);
    float a_ri = aR[node * 8 + head];
    int beg = node * MAXDEG;
    int deg = min(degv[node], MAXDEG);

    float lsum = 0.f;
    float acc[8] = {0.f, 0.f, 0.f, 0.f, 0.f, 0.f, 0.f, 0.f};

    int p = slot;
    int j0 = (p < deg) ? esrc[beg + p] : 0;
    ushort8v hjA = h8[(long)j0 * 32 + lh];
    float alA = aL[j0 * 8 + head];
    int j1 = (p + 2 < deg) ? esrc[beg + p + 2] : 0;

    for (; p < deg; p += 2) {
        // issue next gather before consuming current (2 in flight per slot)
        ushort8v hjB = h8[(long)j1 * 32 + lh];
        float alB = aL[j1 * 8 + head];
        int j2 = (p + 4 < deg) ? esrc[beg + p + 4] : 0;

        float hj[8];
        #pragma unroll
        for (int c = 0; c < 8; c++) hj[c] = bf2f(hjA[c]);
        float prod = hi[0] * hj[0];
        #pragma unroll
        for (int c = 1; c < 8; c++) prod += hi[c] * hj[c];
        prod += __shfl_xor(prod, 1);       // reduce within 4-lane head group
        prod += __shfl_xor(prod, 2);
        float alpha = (alA + a_ri) * __builtin_amdgcn_rcpf(1.f + __expf(-prod));
        alpha = (alpha > 0.f) ? alpha : 0.2f * alpha;      // leaky_relu
        float ex = __expf(alpha);
        lsum += ex;
        #pragma unroll
        for (int c = 0; c < 8; c++) acc[c] += ex * hj[c];

        hjA = hjB; alA = alB; j1 = j2;
    }

    // combine the two edge-slots
    lsum += __shfl_xor(lsum, 32);
    #pragma unroll
    for (int c = 0; c < 8; c++) acc[c] += __shfl_xor(acc[c], 32);

    if (slot == 0) {
        float inv = __builtin_amdgcn_rcpf(lsum + 1e-16f);
        float4 b0 = ((const float4*)bias)[lh * 2];
        float4 b1 = ((const float4*)bias)[lh * 2 + 1];
        float bb[8] = {b0.x, b0.y, b0.z, b0.w, b1.x, b1.y, b1.z, b1.w};
        float r[8];
        #pragma unroll
        for (int c = 0; c < 8; c++) r[c] = acc[c] * inv + bb[c];
        if (MODE == 1) {
            ushort8v o;
            #pragma unroll
            for (int c = 0; c < 8; c++) {
                float v = r[c];
                v = (v > 0.f) ? v : (__expf(v) - 1.f);     // ELU
                o[c] = f2bf(v);
            }
            *(ushort8v*)(out + (long)node * 256 + lh * 8) = o;
        } else {
            int g = batch[node];
            float* ps = psum + g * HC + lh * 8;
            #pragma unroll
            for (int c = 0; c < 8; c++) atomicAdd(&ps[c], r[c]);
            if (lh == 0) atomicAdd(&pcnt[g], 1.f);
        }
    }
}

// ---------------- head: pooled mean @ lin_W + lin_b ----------------

__global__ void final_kernel(const float* __restrict__ psum, const float* __restrict__ pcnt,
                             const float* __restrict__ linW, const float* __restrict__ linb,
                             float* __restrict__ out) {
    int g = blockIdx.x;
    int t = threadIdx.x;
    __shared__ float p[HC];
    float c = fmaxf(pcnt[g], 1.f);
    p[t] = psum[g * HC + t] / c;
    __syncthreads();
    if (t < NCLS) {
        float s = linb[t];
        for (int cch = 0; cch < HC; cch++) s += p[cch] * linW[cch * NCLS + t];
        out[g * NCLS + t] = s;
    }
}

// ---------------- launch ----------------

extern "C" void kernel_launch(void* const* d_in, const int* in_sizes, int n_in,
                              void* d_out, int out_size, void* d_ws, size_t ws_size,
                              hipStream_t stream) {
    const float* x     = (const float*)d_in[0];
    const int*   ei    = (const int*)d_in[1];
    const int*   batch = (const int*)d_in[2];
    const float* W1    = (const float*)d_in[3];
    const float* attL1 = (const float*)d_in[4];
    const float* attR1 = (const float*)d_in[5];
    const float* b1    = (const float*)d_in[6];
    const float* W2    = (const float*)d_in[7];
    const float* attL2 = (const float*)d_in[8];
    const float* attR2 = (const float*)d_in[9];
    const float* b2    = (const float*)d_in[10];
    const float* linW  = (const float*)d_in[11];
    const float* linb  = (const float*)d_in[12];
    float* out = (float*)d_out;

    // workspace layout
    char* w = (char*)d_ws;
    size_t o = 0;
    int* deg    = (int*)(w + o); o += (size_t)NNODE * 4;
    o = (o + 15) & ~(size_t)15;
    int* esrc   = (int*)(w + o); o += (size_t)NNODE * MAXDEG * 4;
    o = (o + 15) & ~(size_t)15;
    ushort* W1t = (ushort*)(w + o); o += (size_t)FIN * HC * 2;
    ushort* W2t = (ushort*)(w + o); o += (size_t)HC * HC * 2;
    o = (o + 15) & ~(size_t)15;
    ushort* hbA = (ushort*)(w + o); o += (size_t)NNODE * HC * 2;
    ushort* hbB = (ushort*)(w + o); o += (size_t)NNODE * HC * 2;
    o = (o + 15) & ~(size_t)15;
    float* aL   = (float*)(w + o); o += (size_t)NNODE * HEADS * 4;
    float* aR   = (float*)(w + o); o += (size_t)NNODE * HEADS * 4;
    float* psum = (float*)(w + o); o += (size_t)NGRAPH * HC * 4;
    float* pcnt = (float*)(w + o); o += (size_t)NGRAPH * 4;

    init_kernel<<<384 + ZB_DEG + ZB_PS, 256, 0, stream>>>(W1, W2, W1t, W2t, deg, psum);

    int eb = (ETOT + 255) / 256;
    fill_slots<<<eb, 256, 0, stream>>>(ei, deg, esrc);

    dim3 gg((NNODE + 63) / 64, HC / 64);
    int ab = (NNODE + 3) / 4;
    // layer 1 (A = fp32 x, converted during LDS staging)
    gemm_mfma<true><<<gg, 256, 0, stream>>>(x, W1t, hbA, attL1, attR1, aL, aR, NNODE, FIN);
    fused_attn<1><<<ab, 256, 0, stream>>>(hbA, deg, esrc, aL, aR, b1, hbB,
                                          batch, psum, pcnt);
    // layer 2 (A = bf16 h); attention pools directly into psum
    gemm_mfma<false><<<gg, 256, 0, stream>>>(hbB, W2t, hbA, attL2, attR2, aL, aR, NNODE, HC);
    fused_attn<2><<<ab, 256, 0, stream>>>(hbA, deg, esrc, aL, aR, b2, (ushort*)nullptr,
                                          batch, psum, pcnt);
    // head
    final_kernel<<<NGRAPH, 256, 0, stream>>>(psum, pcnt, linW, linb, out);
}

// Round 12
// 222.798 us; speedup vs baseline: 1.9619x; 1.9619x over previous
//
#include <hip/hip_runtime.h>
#include <hip/hip_bf16.h>
#include <math.h>

#define NNODE 20000
#define FIN   128
#define HC    256     // HEADS*HID
#define HEADS 8
#define HID   32
#define NEDGE 320000
#define ETOT  (NEDGE + NNODE)
#define NGRAPH 64
#define NCLS  10
#define MAXDEG 64     // P(deg>=64) ~ 1e-17 per node for Binomial(320k,1/20k)+1

typedef __attribute__((ext_vector_type(8))) short short8v;
typedef __attribute__((ext_vector_type(8))) unsigned short ushort8v;
typedef __attribute__((ext_vector_type(4))) float float4v;

__device__ __forceinline__ ushort f2bf(float f) {
    __hip_bfloat16 b = __float2bfloat16(f);
    return *(ushort*)&b;
}
__device__ __forceinline__ float bf2f(ushort u) {
    return __uint_as_float(((unsigned)u) << 16);
}

// ---------------- init: zero deg/psum + transpose/convert W1, W2 -------------

#define ZB_DEG ((NNODE + 255) / 256)                        // 79
#define ZB_PS  ((NGRAPH * HC + NGRAPH + 255) / 256)         // 65

__global__ __launch_bounds__(256) void init_kernel(const float* __restrict__ W1,
                                                   const float* __restrict__ W2,
                                                   ushort* __restrict__ W1t,
                                                   ushort* __restrict__ W2t,
                                                   int* __restrict__ deg,
                                                   float* __restrict__ psum) {
    int b = blockIdx.x;
    if (b < 128) {
        int e = b * 256 + threadIdx.x;
        int k = e >> 8, n = e & 255;
        W1t[(long)n * FIN + k] = f2bf(W1[(long)k * 256 + n]);
    } else if (b < 384) {
        int e = (b - 128) * 256 + threadIdx.x;
        int k = e >> 8, n = e & 255;
        W2t[(long)n * HC + k] = f2bf(W2[(long)k * 256 + n]);
    } else if (b < 384 + ZB_DEG) {
        int i = (b - 384) * 256 + threadIdx.x;
        if (i < NNODE) deg[i] = 0;
    } else {
        int i = (b - 384 - ZB_DEG) * 256 + threadIdx.x;
        if (i < NGRAPH * HC + NGRAPH) psum[i] = 0.f;
    }
}

// ---------------- slot-table CSR: one kernel, no scan ------------------------

__global__ __launch_bounds__(256) void fill_slots(const int* __restrict__ ei,
                                                  int* __restrict__ deg,
                                                  int* __restrict__ esrc) {
    int e = blockIdx.x * blockDim.x + threadIdx.x;
    if (e >= ETOT) return;
    int src, dst;
    if (e < NEDGE) { src = ei[e]; dst = ei[NEDGE + e]; }
    else           { src = e - NEDGE; dst = src; }
    int slot = atomicAdd(&deg[dst], 1);
    if (slot < MAXDEG) esrc[dst * MAXDEG + slot] = src;
}

// ---------------- bf16 MFMA GEMM + fused aL/aR epilogue ----------------------
// C[M,256] = A[M,K] @ Bt[256,K]^T. 64x128 block tile, 4 waves x 32x64 each.
// Per BK=64 iter per wave: 16 MFMA on 12 ds_read_b128 (was 8:8 at 64x64).

template<bool A_FP32>
__global__ __launch_bounds__(256) void gemm_mfma(const void* __restrict__ Aptr,
                                                 const ushort* __restrict__ Bt,
                                                 ushort* __restrict__ C,
                                                 const float* __restrict__ attL,
                                                 const float* __restrict__ attR,
                                                 float* __restrict__ aL,
                                                 float* __restrict__ aR,
                                                 int M, int K) {
    __shared__ __align__(16) ushort As[64][72];    // pitch 72: 2-way conflicts max (free)
    __shared__ __align__(16) ushort Bs[128][72];
    int tid = threadIdx.x;
    int rowBase = blockIdx.x * 64;
    int colBase = blockIdx.y * 128;
    int wave = tid >> 6;
    int l = tid & 63;
    int lm = l & 15;
    int quad = l >> 4;
    int r0 = (wave >> 1) * 32;     // wave's row quadrant (0 or 32)
    int c0 = (wave & 1) * 64;      // wave's col half (0 or 64)

    float4v acc[2][4] = {};

    for (int k0 = 0; k0 < K; k0 += 64) {
        if (A_FP32) {
            const float* A = (const float*)Aptr;
            #pragma unroll
            for (int q = 0; q < 4; q++) {
                int idx = tid + q * 256;          // 1024 float4 chunks (64x64 fp32)
                int r   = idx >> 4;
                int kc  = (idx & 15) * 4;
                int grow = rowBase + r;
                float4 v = make_float4(0.f, 0.f, 0.f, 0.f);
                if (grow < M) v = *(const float4*)(A + (long)grow * K + k0 + kc);
                ushort4 o = { f2bf(v.x), f2bf(v.y), f2bf(v.z), f2bf(v.w) };
                *(ushort4*)&As[r][kc] = o;
            }
        } else {
            const ushort* A = (const ushort*)Aptr;
            #pragma unroll
            for (int q = 0; q < 2; q++) {
                int ch = tid + q * 256;           // 512 ushort8 chunks (64x64 bf16)
                int r  = ch >> 3;
                int kc = (ch & 7) * 8;
                int grow = rowBase + r;
                short8v av = {};
                if (grow < M) av = *(const short8v*)(A + (long)grow * K + k0 + kc);
                *(short8v*)&As[r][kc] = av;
            }
        }
        #pragma unroll
        for (int q = 0; q < 4; q++) {             // 1024 ushort8 chunks (128x64 bf16)
            int ch = tid + q * 256;
            int r  = ch >> 3;
            int kc = (ch & 7) * 8;
            *(short8v*)&Bs[r][kc] =
                *(const short8v*)(Bt + (long)(colBase + r) * K + k0 + kc);
        }
        __syncthreads();
        #pragma unroll
        for (int ks = 0; ks < 64; ks += 32) {
            int kb = ks + quad * 8;
            short8v a0 = *(const short8v*)&As[r0 + lm][kb];
            short8v a1 = *(const short8v*)&As[r0 + 16 + lm][kb];
            short8v b0 = *(const short8v*)&Bs[c0 + lm][kb];
            short8v b1 = *(const short8v*)&Bs[c0 + 16 + lm][kb];
            short8v b2 = *(const short8v*)&Bs[c0 + 32 + lm][kb];
            short8v b3 = *(const short8v*)&Bs[c0 + 48 + lm][kb];
            acc[0][0] = __builtin_amdgcn_mfma_f32_16x16x32_bf16(a0, b0, acc[0][0], 0, 0, 0);
            acc[0][1] = __builtin_amdgcn_mfma_f32_16x16x32_bf16(a0, b1, acc[0][1], 0, 0, 0);
            acc[0][2] = __builtin_amdgcn_mfma_f32_16x16x32_bf16(a0, b2, acc[0][2], 0, 0, 0);
            acc[0][3] = __builtin_amdgcn_mfma_f32_16x16x32_bf16(a0, b3, acc[0][3], 0, 0, 0);
            acc[1][0] = __builtin_amdgcn_mfma_f32_16x16x32_bf16(a1, b0, acc[1][0], 0, 0, 0);
            acc[1][1] = __builtin_amdgcn_mfma_f32_16x16x32_bf16(a1, b1, acc[1][1], 0, 0, 0);
            acc[1][2] = __builtin_amdgcn_mfma_f32_16x16x32_bf16(a1, b2, acc[1][2], 0, 0, 0);
            acc[1][3] = __builtin_amdgcn_mfma_f32_16x16x32_bf16(a1, b3, acc[1][3], 0, 0, 0);
        }
        __syncthreads();
    }

    // D mapping: col = lane&15, row = quad*4 + reg. Wave owns cols cb..cb+63
    // = heads hd0, hd0+1 (32 cols each: frags {0,1} and {2,3}).
    int cb = colBase + c0;
    int hd0 = cb >> 5;
    float al[4], ar[4];
    #pragma unroll
    for (int f = 0; f < 4; f++) {
        al[f] = attL[cb + f * 16 + lm];
        ar[f] = attR[cb + f * 16 + lm];
    }
    #pragma unroll
    for (int mi = 0; mi < 2; mi++) {
        #pragma unroll
        for (int r = 0; r < 4; r++) {
            int row = rowBase + r0 + mi * 16 + quad * 4 + r;
            float pl0 = acc[mi][0][r] * al[0] + acc[mi][1][r] * al[1];
            float pr0 = acc[mi][0][r] * ar[0] + acc[mi][1][r] * ar[1];
            float pl1 = acc[mi][2][r] * al[2] + acc[mi][3][r] * al[3];
            float pr1 = acc[mi][2][r] * ar[2] + acc[mi][3][r] * ar[3];
            #pragma unroll
            for (int s2 = 1; s2 < 16; s2 <<= 1) {   // reduce within 16-lane quad
                pl0 += __shfl_xor(pl0, s2);
                pr0 += __shfl_xor(pr0, s2);
                pl1 += __shfl_xor(pl1, s2);
                pr1 += __shfl_xor(pr1, s2);
            }
            if (row < M) {
                #pragma unroll
                for (int f = 0; f < 4; f++)
                    C[(long)row * 256 + cb + f * 16 + lm] = f2bf(acc[mi][f][r]);
                if (lm == 0) {
                    aL[row * 8 + hd0]     = pl0;
                    aR[row * 8 + hd0]     = pr0;
                    aL[row * 8 + hd0 + 1] = pl1;
                    aR[row * 8 + hd0 + 1] = pr1;
                }
            }
        }
    }
}

// ---------------- fused attention v4: 1 node/wave, 2 slots, 2-stage pipeline -

__global__ __launch_bounds__(256) void fused_attn(const ushort* __restrict__ h,
                                                  const int* __restrict__ degv,
                                                  const int* __restrict__ esrc,
                                                  const float* __restrict__ aL,
                                                  const float* __restrict__ aR,
                                                  const float* __restrict__ bias,
                                                  ushort* __restrict__ out,
                                                  int apply_elu) {
    int wave = threadIdx.x >> 6;
    int node = blockIdx.x * 4 + wave;
    if (node >= NNODE) return;
    int l = threadIdx.x & 63;
    int slot = l >> 5;
    int lh = l & 31;
    int head = lh >> 2;

    const ushort8v* h8 = (const ushort8v*)h;
    ushort8v hiu = h8[(long)node * 32 + lh];
    float hi[8];
    #pragma unroll
    for (int c = 0; c < 8; c++) hi[c] = bf2f(hiu[c]);
    float a_ri = aR[node * 8 + head];
    int beg = node * MAXDEG;
    int deg = min(degv[node], MAXDEG);

    float lsum = 0.f;
    float acc[8] = {0.f, 0.f, 0.f, 0.f, 0.f, 0.f, 0.f, 0.f};

    int p = slot;
    int j0 = (p < deg) ? esrc[beg + p] : 0;
    ushort8v hjA = h8[(long)j0 * 32 + lh];
    float alA = aL[j0 * 8 + head];
    int j1 = (p + 2 < deg) ? esrc[beg + p + 2] : 0;

    for (; p < deg; p += 2) {
        ushort8v hjB = h8[(long)j1 * 32 + lh];
        float alB = aL[j1 * 8 + head];
        int j2 = (p + 4 < deg) ? esrc[beg + p + 4] : 0;

        float hj[8];
        #pragma unroll
        for (int c = 0; c < 8; c++) hj[c] = bf2f(hjA[c]);
        float prod = hi[0] * hj[0];
        #pragma unroll
        for (int c = 1; c < 8; c++) prod += hi[c] * hj[c];
        prod += __shfl_xor(prod, 1);       // reduce within 4-lane head group
        prod += __shfl_xor(prod, 2);
        float alpha = (alA + a_ri) * __builtin_amdgcn_rcpf(1.f + __expf(-prod));
        alpha = (alpha > 0.f) ? alpha : 0.2f * alpha;      // leaky_relu
        float ex = __expf(alpha);
        lsum += ex;
        #pragma unroll
        for (int c = 0; c < 8; c++) acc[c] += ex * hj[c];

        hjA = hjB; alA = alB; j1 = j2;
    }

    lsum += __shfl_xor(lsum, 32);
    #pragma unroll
    for (int c = 0; c < 8; c++) acc[c] += __shfl_xor(acc[c], 32);

    if (slot == 0) {
        float inv = __builtin_amdgcn_rcpf(lsum + 1e-16f);
        float4 b0 = ((const float4*)bias)[lh * 2];
        float4 b1 = ((const float4*)bias)[lh * 2 + 1];
        float bb[8] = {b0.x, b0.y, b0.z, b0.w, b1.x, b1.y, b1.z, b1.w};
        ushort8v o;
        #pragma unroll
        for (int c = 0; c < 8; c++) {
            float r = acc[c] * inv + bb[c];
            if (apply_elu) r = (r > 0.f) ? r : (__expf(r) - 1.f);
            o[c] = f2bf(r);
        }
        *(ushort8v*)(out + (long)node * 256 + lh * 8) = o;
    }
}

// ---------------- pooling (parallel segmented atomics) + head ----------------
// Per-block 64-node local accumulation first -> ~320K atomics total (16x fewer
// than direct per-node atomics; R11 showed direct atomics serialize at 275 us).

__global__ __launch_bounds__(256) void pool_kernel(const ushort* __restrict__ h,
                                                   const int* __restrict__ batch,
                                                   float* __restrict__ psum,
                                                   float* __restrict__ pcnt) {
    int t = threadIdx.x;
    int n0 = blockIdx.x * 64;
    int n1 = min(n0 + 64, NNODE);
    if (n0 >= NNODE) return;
    float accv = 0.f;
    int gcur = batch[n0];
    for (int n = n0; n < n1; ++n) {
        int g = batch[n];
        if (g != gcur) {
            atomicAdd(&psum[gcur * HC + t], accv);
            accv = 0.f;
            gcur = g;
        }
        accv += bf2f(h[(long)n * HC + t]);
    }
    atomicAdd(&psum[gcur * HC + t], accv);
    if (t == 0) {
        int cnt = 0;
        int gc = batch[n0];
        for (int n = n0; n < n1; ++n) {
            int g = batch[n];
            if (g != gc) { atomicAdd(&pcnt[gc], (float)cnt); cnt = 0; gc = g; }
            cnt++;
        }
        atomicAdd(&pcnt[gc], (float)cnt);
    }
}

__global__ void final_kernel(const float* __restrict__ psum, const float* __restrict__ pcnt,
                             const float* __restrict__ linW, const float* __restrict__ linb,
                             float* __restrict__ out) {
    int g = blockIdx.x;
    int t = threadIdx.x;
    __shared__ float p[HC];
    float c = fmaxf(pcnt[g], 1.f);
    p[t] = psum[g * HC + t] / c;
    __syncthreads();
    if (t < NCLS) {
        float s = linb[t];
        for (int cch = 0; cch < HC; cch++) s += p[cch] * linW[cch * NCLS + t];
        out[g * NCLS + t] = s;
    }
}

// ---------------- launch ----------------

extern "C" void kernel_launch(void* const* d_in, const int* in_sizes, int n_in,
                              void* d_out, int out_size, void* d_ws, size_t ws_size,
                              hipStream_t stream) {
    const float* x     = (const float*)d_in[0];
    const int*   ei    = (const int*)d_in[1];
    const int*   batch = (const int*)d_in[2];
    const float* W1    = (const float*)d_in[3];
    const float* attL1 = (const float*)d_in[4];
    const float* attR1 = (const float*)d_in[5];
    const float* b1    = (const float*)d_in[6];
    const float* W2    = (const float*)d_in[7];
    const float* attL2 = (const float*)d_in[8];
    const float* attR2 = (const float*)d_in[9];
    const float* b2    = (const float*)d_in[10];
    const float* linW  = (const float*)d_in[11];
    const float* linb  = (const float*)d_in[12];
    float* out = (float*)d_out;

    // workspace layout
    char* w = (char*)d_ws;
    size_t o = 0;
    int* deg    = (int*)(w + o); o += (size_t)NNODE * 4;
    o = (o + 15) & ~(size_t)15;
    int* esrc   = (int*)(w + o); o += (size_t)NNODE * MAXDEG * 4;
    o = (o + 15) & ~(size_t)15;
    ushort* W1t = (ushort*)(w + o); o += (size_t)FIN * HC * 2;
    ushort* W2t = (ushort*)(w + o); o += (size_t)HC * HC * 2;
    o = (o + 15) & ~(size_t)15;
    ushort* hbA = (ushort*)(w + o); o += (size_t)NNODE * HC * 2;
    ushort* hbB = (ushort*)(w + o); o += (size_t)NNODE * HC * 2;
    o = (o + 15) & ~(size_t)15;
    float* aL   = (float*)(w + o); o += (size_t)NNODE * HEADS * 4;
    float* aR   = (float*)(w + o); o += (size_t)NNODE * HEADS * 4;
    float* psum = (float*)(w + o); o += (size_t)NGRAPH * HC * 4;
    float* pcnt = (float*)(w + o); o += (size_t)NGRAPH * 4;

    init_kernel<<<384 + ZB_DEG + ZB_PS, 256, 0, stream>>>(W1, W2, W1t, W2t, deg, psum);

    int eb = (ETOT + 255) / 256;
    fill_slots<<<eb, 256, 0, stream>>>(ei, deg, esrc);

    dim3 gg((NNODE + 63) / 64, HC / 128);   // 313 x 2 = 626 blocks
    int ab = (NNODE + 3) / 4;
    // layer 1 (A = fp32 x, converted during LDS staging)
    gemm_mfma<true><<<gg, 256, 0, stream>>>(x, W1t, hbA, attL1, attR1, aL, aR, NNODE, FIN);
    fused_attn<<<ab, 256, 0, stream>>>(hbA, deg, esrc, aL, aR, b1, hbB, 1);
    // layer 2 (A = bf16 h)
    gemm_mfma<false><<<gg, 256, 0, stream>>>(hbB, W2t, hbA, attL2, attR2, aL, aR, NNODE, HC);
    fused_attn<<<ab, 256, 0, stream>>>(hbA, deg, esrc, aL, aR, b2, hbB, 0);
    // pool + head
    pool_kernel<<<(NNODE + 63) / 64, 256, 0, stream>>>(hbB, batch, psum, pcnt);
    final_kernel<<<NGRAPH, 256, 0, stream>>>(psum, pcnt, linW, linb, out);
}